// Round 6
// baseline (597.256 us; speedup 1.0000x reference)
//
#include <hip/hip_runtime.h>
#include <stdint.h>

// B=8192, N=17, C=512, H=8, HD=64 — f16 pipeline (inputs fp32)
// Fused qkv-GEMM (head-grouped W) + MFMA attention epilogue; 2 blocks/CU.

typedef __attribute__((ext_vector_type(4))) float f32x4;
typedef _Float16 f16x8 __attribute__((ext_vector_type(8)));
typedef _Float16 f16x2 __attribute__((ext_vector_type(2)));

__device__ __forceinline__ unsigned short f2h(float f) {
  return __builtin_bit_cast(unsigned short, (_Float16)f);
}
__device__ __forceinline__ float h2f(unsigned short h) {
  return (float)__builtin_bit_cast(_Float16, h);
}
__device__ __forceinline__ float fdot2u(uint32_t a, uint32_t b, float c) {
  return __builtin_amdgcn_fdot2(__builtin_bit_cast(f16x2, a),
                                __builtin_bit_cast(f16x2, b), c, false);
}

#define GLOAD_LDS16(gptr, lptr)                                          \
  __builtin_amdgcn_global_load_lds(                                      \
      (__attribute__((address_space(1))) void*)(gptr),                   \
      (__attribute__((address_space(3))) void*)(lptr), 16, 0, 0)

__device__ __forceinline__ f32x4 mfma16(f16x8 a, f16x8 b, f32x4 c) {
  return __builtin_amdgcn_mfma_f32_16x16x32_f16(a, b, c, 0, 0, 0);
}

// ---------------- cast fp32 -> f16, 4 elems/thread ----------------
__global__ __launch_bounds__(256) void k_cvt(const float* __restrict__ in,
                                             unsigned short* __restrict__ out,
                                             long n4) {
  long i = (long)blockIdx.x * 256 + threadIdx.x;
  if (i >= n4) return;
  float4 a = reinterpret_cast<const float4*>(in)[i];
  ushort4 o;
  o.x = f2h(a.x); o.y = f2h(a.y); o.z = f2h(a.z); o.w = f2h(a.w);
  reinterpret_cast<ushort4*>(out)[i] = o;
}

// ---- transpose-cast W[K][Norig] fp32 -> Wt[N][K] f16; PERM = head-group ----
template <bool PERM>
__global__ __launch_bounds__(256) void k_cvt_t(const float* __restrict__ W,
                                               unsigned short* __restrict__ Wt,
                                               int K, int Norig) {
  int i = blockIdx.x * 256 + threadIdx.x;
  if (i >= K * Norig) return;
  int np = i / K, k = i - np * K;
  int n = np;
  if (PERM) {
    int h = np / 192, rem = np - h * 192;
    int t = rem >> 6, d = rem & 63;
    n = t * 512 + h * 64 + d;
  }
  Wt[i] = f2h(W[(size_t)k * Norig + n]);
}

// ---- permute bias: bqp[n'] = b[n] ----
__global__ __launch_bounds__(256) void k_permb(const float* __restrict__ b,
                                               float* __restrict__ bqp) {
  int np = blockIdx.x * 256 + threadIdx.x;
  if (np >= 1536) return;
  int h = np / 192, rem = np - h * 192;
  int t = rem >> 6, d = rem & 63;
  bqp[np] = b[t * 512 + h * 64 + d];
}

// ============ fused qkv-GEMM + MFMA attention ============
// BM=128 (7 batches), BN=192 (one head q|k|v), BK=64, KT=8,
// 512 thr = 8 waves (2M x 4N), per-wave 64x48.
// Staging LDS: dbuf x (A 128x64 + B 192x64) f16 = 81,920 B -> 2 blocks/CU.
// Epilogue overlays (shorts): SQ[128][136] @0, VT[8][64][32] @17408,
// PL[8][16][40] @33792, SE[8][34] f32 @38912 (byte 77824). End 78,912 B.
#define FBUF 20480
#define SQ_OFF 0
#define VT_OFF 17408
#define PL_OFF 33792
#define SE_OFF 38912

__global__ __launch_bounds__(512, 4) void k_fused(
    const unsigned short* __restrict__ A,   // xb  [139264][512] f16
    const unsigned short* __restrict__ Bt,  // wqt'[1536][512] f16
    const float* __restrict__ bqp,          // permuted bias [1536]
    const float* __restrict__ outer,        // [8][17][17]
    const float* __restrict__ alpha_p,      // [1]
    unsigned short* __restrict__ ao) {      // [139264][512] f16
  __shared__ __align__(16) unsigned short smem[2 * FBUF];  // 81,920 B

  const int tid = threadIdx.x;
  const int w = tid >> 6, lane = tid & 63;
  const int wm = w >> 2, wn = w & 3;
  const int lr = lane & 15, lk = lane >> 4;

  const int bid = (blockIdx.x & 7) * ((int)gridDim.x >> 3) + (blockIdx.x >> 3);
  const int mt = bid >> 3, h = bid & 7;
  const int batch0 = mt * 7;
  const int brow = batch0 * 17;
  const int bcol = h * 192;

  const int srowl = lane >> 3;
  const int scol = ((lane & 7) ^ srowl) << 3;

  f32x4 acc[4][3];
#pragma unroll
  for (int m = 0; m < 4; m++)
#pragma unroll
    for (int n = 0; n < 3; n++) acc[m][n] = f32x4{0.f, 0.f, 0.f, 0.f};

  auto STAGE = [&](int t, int buf) {
    unsigned short* dstbase = smem + buf * FBUF;
#pragma unroll
    for (int s5 = 0; s5 < 5; ++s5) {
      const int s = w + s5 * 8;
      unsigned short* dst = dstbase + s * 512;
      const unsigned short* src;
      if (s < 16) {
        int gr = brow + s * 8 + srowl;
        if (gr > 139263) gr = 139263;
        src = A + (size_t)gr * 512 + t * 64 + scol;
      } else {
        int r = (s - 16) * 8 + srowl;
        src = Bt + (size_t)(bcol + r) * 512 + t * 64 + scol;
      }
      GLOAD_LDS16(src, dst);
    }
  };

  STAGE(0, 0);
  asm volatile("s_waitcnt vmcnt(0)" ::: "memory");
  __builtin_amdgcn_s_barrier();

  for (int t = 0; t < 8; ++t) {
    const int ub = (t & 1) * FBUF;
    if (t < 7) STAGE(t + 1, (t + 1) & 1);
    const unsigned short* sa = smem + ub + (wm * 64 + lr) * 64;
    const unsigned short* sb = smem + ub + 8192 + (wn * 48 + lr) * 64;
#pragma unroll
    for (int kk = 0; kk < 2; ++kk) {
      const int gx = (((kk << 2) + lk) ^ (lr & 7)) << 3;
      f16x8 av0 = *(const f16x8*)(sa + gx);
      f16x8 av1 = *(const f16x8*)(sa + 1024 + gx);
      f16x8 av2 = *(const f16x8*)(sa + 2048 + gx);
      f16x8 av3 = *(const f16x8*)(sa + 3072 + gx);
      f16x8 bv0 = *(const f16x8*)(sb + gx);
      f16x8 bv1 = *(const f16x8*)(sb + 1024 + gx);
      f16x8 bv2 = *(const f16x8*)(sb + 2048 + gx);
      acc[0][0] = mfma16(av0, bv0, acc[0][0]);
      acc[0][1] = mfma16(av0, bv1, acc[0][1]);
      acc[0][2] = mfma16(av0, bv2, acc[0][2]);
      acc[1][0] = mfma16(av1, bv0, acc[1][0]);
      acc[1][1] = mfma16(av1, bv1, acc[1][1]);
      acc[1][2] = mfma16(av1, bv2, acc[1][2]);
      acc[2][0] = mfma16(av2, bv0, acc[2][0]);
      acc[2][1] = mfma16(av2, bv1, acc[2][1]);
      acc[2][2] = mfma16(av2, bv2, acc[2][2]);
      acc[3][0] = mfma16(av3, bv0, acc[3][0]);
      acc[3][1] = mfma16(av3, bv1, acc[3][1]);
      acc[3][2] = mfma16(av3, bv2, acc[3][2]);
    }
    asm volatile("s_waitcnt vmcnt(0)" ::: "memory");
    __builtin_amdgcn_s_barrier();
  }

  // ---- epi-1: acc(+bias) -> scratch: q,k row-major [tok][136]; v -> vT ----
  unsigned short* SQ = smem + SQ_OFF;
  unsigned short* VT = smem + VT_OFF;   // [8][64][32] per-batch v^T
  unsigned short* PL = smem + PL_OFF;   // [8][16][40]
  float* SE = (float*)(smem + SE_OFF);  // [8][34]
  {
    const int er0 = wm * 64 + (lane >> 4) * 4;
    const int ec0 = wn * 48 + lr;
#pragma unroll
    for (int nf = 0; nf < 3; ++nf) {
      const int col = ec0 + nf * 16;
      const float bv = bqp[bcol + col];
#pragma unroll
      for (int mf = 0; mf < 4; ++mf) {
        const int t0 = er0 + mf * 16;
        float v0 = acc[mf][nf][0] + bv, v1 = acc[mf][nf][1] + bv;
        float v2 = acc[mf][nf][2] + bv, v3 = acc[mf][nf][3] + bv;
        if (col < 128) {  // q,k: scatter b16, stride 136
          SQ[(t0 + 0) * 136 + col] = f2h(v0);
          SQ[(t0 + 1) * 136 + col] = f2h(v1);
          SQ[(t0 + 2) * 136 + col] = f2h(v2);
          SQ[(t0 + 3) * 136 + col] = f2h(v3);
        } else {  // v: vT[bat][d][local], 4 scattered b16 (runs may split)
          const int d = col - 128;
#pragma unroll
          for (int rr = 0; rr < 4; ++rr) {
            const int tt = t0 + rr;
            const int bb = tt / 17, tl = tt - bb * 17;
            float vv = (rr == 0 ? v0 : rr == 1 ? v1 : rr == 2 ? v2 : v3);
            if (bb < 7) VT[bb * 2048 + d * 32 + tl] = f2h(vv);
          }
        }
      }
    }
  }
  __syncthreads();

  // ---- epi-2: per-wave MFMA attention, batch = w ----
  const int nb = min(7, 8192 - batch0);
  if (w < nb) {
    const float alpha = alpha_p[0];
    const int base = w * 17;
    unsigned short* PLw = PL + w * 640;
    unsigned short* VTw = VT + w * 2048;
    float* SEw = SE + w * 34;

    // zero P cols 16..39 (rows 0..15) — junk-V killer
    for (int i = lane; i < 16 * 24; i += 64)
      PLw[(i / 24) * 40 + 16 + (i % 24)] = 0;

    // logits main 16x16, K=64 via 2 MFMA
    f32x4 sAcc = f32x4{0.f, 0.f, 0.f, 0.f};
#pragma unroll
    for (int kk = 0; kk < 2; ++kk) {
      f16x8 qa = *(const f16x8*)(SQ + (base + lr) * 136 + kk * 32 + lk * 8);
      f16x8 kb = *(const f16x8*)(SQ + (base + lr) * 136 + 64 + kk * 32 + lk * 8);
      sAcc = mfma16(qa, kb, sAcc);
    }

    // edge dots: lanes 0..15 -> (r,16); lanes 16..32 -> (16,m)
    if (lane < 33) {
      const int r_ = (lane < 16) ? lane : 16;
      const int m_ = (lane < 16) ? 16 : lane - 16;
      const uint4* qr = (const uint4*)(SQ + (base + r_) * 136);
      const uint4* kr = (const uint4*)(SQ + (base + m_) * 136 + 64);
      float dt = 0.f;
#pragma unroll
      for (int c = 0; c < 8; ++c) {
        uint4 qa = qr[c], ka = kr[c];
        dt = fdot2u(qa.x, ka.x, dt);
        dt = fdot2u(qa.y, ka.y, dt);
        dt = fdot2u(qa.z, ka.z, dt);
        dt = fdot2u(qa.w, ka.w, dt);
      }
      float sv = (dt + alpha * outer[h * 289 + r_ * 17 + m_]) * 0.125f;
      SEw[(lane < 16) ? lane : (17 + m_)] = sv;
    }
    __builtin_amdgcn_wave_barrier();
    asm volatile("" ::: "memory");

    // softmax on C-layout: col=m=lr, rows g4+j
    const int g4 = (lane >> 4) * 4;
    float sp[4], rmax[4], p[4], pe[4], rsum[4], inv[4];
#pragma unroll
    for (int j = 0; j < 4; ++j) {
      sp[j] = (sAcc[j] + alpha * outer[h * 289 + (g4 + j) * 17 + lr]) * 0.125f;
      rmax[j] = sp[j];
    }
#pragma unroll
    for (int d = 1; d < 16; d <<= 1)
#pragma unroll
      for (int j = 0; j < 4; ++j)
        rmax[j] = fmaxf(rmax[j], __shfl_xor(rmax[j], d));
#pragma unroll
    for (int j = 0; j < 4; ++j) {
      float ec = SEw[g4 + j];
      rmax[j] = fmaxf(rmax[j], ec);
      p[j] = __expf(sp[j] - rmax[j]);
      pe[j] = __expf(ec - rmax[j]);
      rsum[j] = p[j];
    }
#pragma unroll
    for (int d = 1; d < 16; d <<= 1)
#pragma unroll
      for (int j = 0; j < 4; ++j) rsum[j] += __shfl_xor(rsum[j], d);
#pragma unroll
    for (int j = 0; j < 4; ++j) {
      rsum[j] += pe[j];
      inv[j] = 1.f / rsum[j];
      PLw[(g4 + j) * 40 + lr] = f2h(p[j]);
    }
    if (lr == 0)
#pragma unroll
      for (int j = 0; j < 4; ++j) PLw[(g4 + j) * 40 + 16] = f2h(pe[j]);
    __builtin_amdgcn_wave_barrier();
    asm volatile("" ::: "memory");

    // PV: 4 MFMA (K=32: m 0..16 real, 17..31 P=0)
    f16x8 pa = *(const f16x8*)(PLw + lr * 40 + lk * 8);
    f32x4 o[4];
#pragma unroll
    for (int nf = 0; nf < 4; ++nf) {
      f16x8 vb = *(const f16x8*)(VTw + (nf * 16 + lr) * 32 + lk * 8);
      o[nf] = mfma16(pa, vb, f32x4{0.f, 0.f, 0.f, 0.f});
    }
    // store rows 0..15
    const size_t gr0 = (size_t)(brow + base) * 512 + h * 64;
#pragma unroll
    for (int nf = 0; nf < 4; ++nf)
#pragma unroll
      for (int j = 0; j < 4; ++j)
        ao[gr0 + (size_t)(g4 + j) * 512 + nf * 16 + lr] =
            f2h(o[nf][j] * inv[j]);

    // row 16: VALU (lane = d)
    {
      float mx16 = -1e30f;
#pragma unroll 1
      for (int m = 0; m < 17; ++m) mx16 = fmaxf(mx16, SEw[17 + m]);
      float o16 = 0.f, s16 = 0.f;
#pragma unroll 1
      for (int m = 0; m < 17; ++m) {
        float pm = __expf(SEw[17 + m] - mx16);
        s16 += pm;
        o16 += pm * h2f(VTw[lane * 32 + m]);
      }
      ao[gr0 + (size_t)16 * 512 + lane] = f2h(o16 / s16);
    }
  }
}

// ============ proj GEMM: 128x128 tile, 2 blocks/CU (unchanged) ============
#define PBUF 16384

__global__ __launch_bounds__(512, 4) void k_proj(
    const unsigned short* __restrict__ A,   // ao [139264][512] f16
    const unsigned short* __restrict__ Bt,  // wpt [512][512] f16
    const float* __restrict__ bias,         // [512]
    float* __restrict__ C) {                // [139264][512] fp32
  __shared__ __align__(16) unsigned short smem[2 * PBUF];

  const int tid = threadIdx.x;
  const int w = tid >> 6, lane = tid & 63;
  const int wm = w >> 2, wn = w & 3;
  const int lr = lane & 15, lk = lane >> 4;

  const int bid = (blockIdx.x & 7) * ((int)gridDim.x >> 3) + (blockIdx.x >> 3);
  const int brow = (bid >> 2) << 7;
  const int bcol = (bid & 3) << 7;

  const int srowl = lane >> 3;
  const int scol = ((lane & 7) ^ srowl) << 3;

  f32x4 acc[4][2];
#pragma unroll
  for (int m = 0; m < 4; m++)
#pragma unroll
    for (int n = 0; n < 2; n++) acc[m][n] = f32x4{0.f, 0.f, 0.f, 0.f};

  auto STAGE = [&](int t, int buf) {
    unsigned short* dstbase = smem + buf * PBUF;
#pragma unroll
    for (int s4 = 0; s4 < 4; ++s4) {
      const int s = w + s4 * 8;
      unsigned short* dst = dstbase + s * 512;
      const unsigned short* src =
          (s < 16) ? A + (size_t)(brow + s * 8 + srowl) * 512 + t * 64 + scol
                   : Bt + (size_t)(bcol + (s - 16) * 8 + srowl) * 512 + t * 64 + scol;
      GLOAD_LDS16(src, dst);
    }
  };

  STAGE(0, 0);
  asm volatile("s_waitcnt vmcnt(0)" ::: "memory");
  __builtin_amdgcn_s_barrier();

  for (int t = 0; t < 8; ++t) {
    const int ub = (t & 1) * PBUF;
    if (t < 7) STAGE(t + 1, (t + 1) & 1);
    const unsigned short* sa = smem + ub + (wm * 64 + lr) * 64;
    const unsigned short* sb = smem + ub + 8192 + (wn * 32 + lr) * 64;
#pragma unroll
    for (int kk = 0; kk < 2; ++kk) {
      const int gx = (((kk << 2) + lk) ^ (lr & 7)) << 3;
      f16x8 av0 = *(const f16x8*)(sa + gx);
      f16x8 av1 = *(const f16x8*)(sa + 1024 + gx);
      f16x8 av2 = *(const f16x8*)(sa + 2048 + gx);
      f16x8 av3 = *(const f16x8*)(sa + 3072 + gx);
      f16x8 bv0 = *(const f16x8*)(sb + gx);
      f16x8 bv1 = *(const f16x8*)(sb + 1024 + gx);
      acc[0][0] = mfma16(av0, bv0, acc[0][0]);
      acc[0][1] = mfma16(av0, bv1, acc[0][1]);
      acc[1][0] = mfma16(av1, bv0, acc[1][0]);
      acc[1][1] = mfma16(av1, bv1, acc[1][1]);
      acc[2][0] = mfma16(av2, bv0, acc[2][0]);
      acc[2][1] = mfma16(av2, bv1, acc[2][1]);
      acc[3][0] = mfma16(av3, bv0, acc[3][0]);
      acc[3][1] = mfma16(av3, bv1, acc[3][1]);
    }
    asm volatile("s_waitcnt vmcnt(0)" ::: "memory");
    __builtin_amdgcn_s_barrier();
  }

  const int orow = brow + wm * 64 + (lane >> 4) * 4;
  const int ocol0 = bcol + wn * 32 + lr;
#pragma unroll
  for (int n = 0; n < 2; n++) {
    const int col = ocol0 + n * 16;
    const float bv = bias[col];
#pragma unroll
    for (int m = 0; m < 4; m++) {
      const int row = orow + m * 16;
#pragma unroll
      for (int r = 0; r < 4; r++)
        C[(size_t)(row + r) * 512 + col] = acc[m][n][r] + bv;
    }
  }
}

// ---------------- launch ----------------
extern "C" void kernel_launch(void* const* d_in, const int* in_sizes, int n_in,
                              void* d_out, int out_size, void* d_ws,
                              size_t ws_size, hipStream_t stream) {
  const float* x      = (const float*)d_in[0];
  const float* W_qkv  = (const float*)d_in[1];
  const float* b_qkv  = (const float*)d_in[2];
  const float* outer  = (const float*)d_in[3];
  const float* alpha  = (const float*)d_in[4];
  const float* W_proj = (const float*)d_in[5];
  const float* b_proj = (const float*)d_in[6];

  char* ws = (char*)d_ws;
  unsigned short* xb  = (unsigned short*)(ws);              // 142,606,336 B
  unsigned short* ao  = (unsigned short*)(ws + 142606336);  // 142,606,336 B
  unsigned short* wqt = (unsigned short*)(ws + 285212672);  // 1,572,864 B
  unsigned short* wpt = (unsigned short*)(ws + 286785536);  // 524,288 B
  float*          bqp = (float*)(ws + 287309824);           // 6,144 B

  k_cvt<<<dim3(69632), dim3(256), 0, stream>>>(x, xb, 17825792L);
  k_cvt_t<true><<<dim3(3072), dim3(256), 0, stream>>>(W_qkv, wqt, 512, 1536);
  k_cvt_t<false><<<dim3(1024), dim3(256), 0, stream>>>(W_proj, wpt, 512, 512);
  k_permb<<<dim3(6), dim3(256), 0, stream>>>(b_qkv, bqp);

  // fused qkv-GEMM + attention: 1171 row-tiles (7 batches each) x 8 heads
  k_fused<<<dim3(9368), dim3(512), 0, stream>>>(xb, wqt, bqp, outer, alpha, ao);

  // proj GEMM: 1088 row-tiles x 4 col-tiles
  k_proj<<<dim3(4352), dim3(512), 0, stream>>>(ao, wpt, b_proj, (float*)d_out);
}